// Round 14
// baseline (3457.548 us; speedup 1.0000x reference)
//
#include <hip/hip_runtime.h>
#include <hip/hip_bf16.h>

// Qwen2 decoder-layer fragment (Q path only — K/V are dead downstream):
//   h = rmsnorm(x, ln_w); q = h@Wq^T + bq; q = rope(q, pos); out = q@Wo^T + x
// out fp32 [8192, 3584].

#define HIDDEN   3584
#define NQ       3584
#define NTOK     8192
#define NPAIR    64
#define EPSV     1e-6f

typedef __hip_bfloat16 bf16;
typedef __bf16 bf16x8 __attribute__((ext_vector_type(8)));
typedef float  f32x4  __attribute__((ext_vector_type(4)));

static __device__ __forceinline__ unsigned short f2bu(float f) {
  bf16 h = __float2bfloat16(f);
  return __builtin_bit_cast(unsigned short, h);
}
static __device__ __forceinline__ void stv(float* p, float v) { *p = v; }
static __device__ __forceinline__ void stv(bf16* p, float v) { *p = __float2bfloat16(v); }

// ---------------- fp32 -> bf16 weight conversion ----------------
__global__ __launch_bounds__(256)
void cvt_f32_bf16(const float* __restrict__ s, bf16* __restrict__ d, int n4) {
  int i = blockIdx.x * 256 + threadIdx.x;
  if (i >= n4) return;
  float4 f = ((const float4*)s)[i];
  ushort4 o;
  o.x = f2bu(f.x); o.y = f2bu(f.y); o.z = f2bu(f.z); o.w = f2bu(f.w);
  ((ushort4*)d)[i] = o;
}

// ---------------- RMSNorm: x fp32 [row, 3584] -> h bf16 ----------------
__global__ __launch_bounds__(256)
void rmsnorm_k(const float* __restrict__ x, const float* __restrict__ w,
               bf16* __restrict__ h) {
  const int row = blockIdx.x;
  const int t = threadIdx.x;
  const float4* xr = (const float4*)(x + (size_t)row * HIDDEN);
  const float4* wr = (const float4*)w;

  float4 v0 = xr[t], v1 = xr[t + 256], v2 = xr[t + 512];
  float4 v3 = make_float4(0.f, 0.f, 0.f, 0.f);
  if (t < 128) v3 = xr[t + 768];

  float ss = v0.x*v0.x + v0.y*v0.y + v0.z*v0.z + v0.w*v0.w
           + v1.x*v1.x + v1.y*v1.y + v1.z*v1.z + v1.w*v1.w
           + v2.x*v2.x + v2.y*v2.y + v2.z*v2.z + v2.w*v2.w
           + v3.x*v3.x + v3.y*v3.y + v3.z*v3.z + v3.w*v3.w;

#pragma unroll
  for (int off = 32; off > 0; off >>= 1) ss += __shfl_down(ss, off);
  __shared__ float red[4];
  if ((t & 63) == 0) red[t >> 6] = ss;
  __syncthreads();
  float tot = red[0] + red[1] + red[2] + red[3];
  float scale = rsqrtf(tot * (1.0f / HIDDEN) + EPSV);

  ushort4* hr = (ushort4*)(h + (size_t)row * HIDDEN);
  float4 w0 = wr[t], w1 = wr[t + 256], w2 = wr[t + 512];
  ushort4 o;
  o.x = f2bu(v0.x*scale*w0.x); o.y = f2bu(v0.y*scale*w0.y);
  o.z = f2bu(v0.z*scale*w0.z); o.w = f2bu(v0.w*scale*w0.w);
  hr[t] = o;
  o.x = f2bu(v1.x*scale*w1.x); o.y = f2bu(v1.y*scale*w1.y);
  o.z = f2bu(v1.z*scale*w1.z); o.w = f2bu(v1.w*scale*w1.w);
  hr[t + 256] = o;
  o.x = f2bu(v2.x*scale*w2.x); o.y = f2bu(v2.y*scale*w2.y);
  o.z = f2bu(v2.z*scale*w2.z); o.w = f2bu(v2.w*scale*w2.w);
  hr[t + 512] = o;
  if (t < 128) {
    float4 w3 = wr[t + 768];
    o.x = f2bu(v3.x*scale*w3.x); o.y = f2bu(v3.y*scale*w3.y);
    o.z = f2bu(v3.z*scale*w3.z); o.w = f2bu(v3.w*scale*w3.w);
    hr[t + 768] = o;
  }
}

// ---------------- per-token rope table ----------------
__global__ __launch_bounds__(256)
void rope_tab_k(const int* __restrict__ pos, float2* __restrict__ tab) {
  int idx = blockIdx.x * 256 + threadIdx.x;   // NTOK*64
  int t = idx >> 6;
  int i = idx & 63;
  float inv = exp2f(-(float)i * (19.931568569324174f / 64.0f));
  float ang = (float)pos[t] * inv;
  float s, c;
  sincosf(ang, &s, &c);
  tab[idx] = make_float2(c, s);
}

// ---------------- in-place neox rope on q bf16 [NTOK, 28, 128] ----------------
__global__ __launch_bounds__(256)
void rope_apply_k(bf16* __restrict__ q, const float2* __restrict__ tab) {
  const int t = blockIdx.x;
  bf16* qt = q + (size_t)t * NQ;
  const float2* tb = tab + (size_t)t * NPAIR;
  for (int j = threadIdx.x; j < 28 * NPAIR; j += 256) {
    int head = j >> 6;
    int i = j & 63;
    float2 cs = tb[i];
    int base = head * 128 + i;
    float x1 = __bfloat162float(qt[base]);
    float x2 = __bfloat162float(qt[base + 64]);
    qt[base]      = __float2bfloat16(x1 * cs.x - x2 * cs.y);
    qt[base + 64] = __float2bfloat16(x2 * cs.x + x1 * cs.y);
  }
}

// ==== 256x256 bf16 GEMM (C = A * B^T), BK=32, 2 blocks/CU co-resident =======
// R14: combine 256^2 arithmetic intensity (FETCH ~294MB, R9) with
// co-residency (R12 mechanism: sibling block fills barrier/drain stalls —
// m97/m114). BK=32 -> LDS = 2buf x (A 16KB + B 16KB) = 64 KiB -> 2 blocks/CU.
// Per-tile balance: LDS pipe 96KB reads + 32KB writes ~ 1024 cyc < MFMA
// 1242 cyc/SIMD -> compute-bound.
// 8 waves (2M x 4N), per-wave 128x64 out (8 m-frags x 4 n-frags), 32 MFMA
// per tile (K=32 = one 16x16x32 MFMA per frag-pair). 2 phases/tile:
//  ph0: read B [4 ds] + A m0-3 [4 ds] from buf u; stage WHOLE tile t+1
//       (A 2 + B 2 instr) -> buf u^1; BAR; 16 MFMA; BAR
//  ph1: read A m4-7 [4 ds]; BAR; 16 MFMA; VMW(0); BAR
// VMW(0)+BAR at end of tile: all 4 stage instrs (issued ph0, 1.5-2 phases
// ~1000-1400 cyc cover >= HBM latency) drained in every wave before any
// wave's next ph0 reads. Full-drain stall is filled by the co-resident
// sibling block (m97 ran full drains at 3 blocks/CU -> 874-912 TF).
// WAR: stages write buf u^1, whose last reads completed before tile t-1's
// trailing barrier. Reads ordered after VMW by its asm clobber.
// Swizzle (BK=32): 4 slots of 16B/row; slot' = slot ^ (row&3) involution;
// gload_lds dest linear, global source pre-swizzled, ds_read swizzled.
#define BMT 256
#define BNT 256
#define BKT 32

#define BARRIER() __builtin_amdgcn_s_barrier()
#define VMW(n)    asm volatile("s_waitcnt vmcnt(" #n ")" ::: "memory")

template <int MODE, typename OutT>   // MODE 0: +bias[col] -> OutT; MODE 1: +resid[row,col]
__global__ __launch_bounds__(512, 4)
void gemm256(const bf16* __restrict__ A, const bf16* __restrict__ B,
             const float* __restrict__ aux, OutT* __restrict__ C,
             int M, int N, int K) {
  __shared__ __align__(16) bf16 sA[2][BMT][BKT];   // 32 KiB
  __shared__ __align__(16) bf16 sB[2][BNT][BKT];   // 32 KiB

  const int tid  = threadIdx.x;
  const int wave = tid >> 6;     // 0..7
  const int lane = tid & 63;
  const int wm   = wave >> 2;    // 0..1  (128-row half)
  const int wn   = wave & 3;     // 0..3  (64-col quarter)
  const int fr   = lane & 15;
  const int ks   = lane >> 4;    // 0..3 (k-chunk of 8)
  const int sx   = fr & 3;       // read-side slot XOR = row & 3

  // bijective XCD swizzle, bn-fast within an XCD (A panel hot in XCD L2)
  const int nwg = gridDim.x;           // 448, % 8 == 0
  const int cpx = nwg >> 3;
  const int swz = (blockIdx.x & 7) * cpx + (blockIdx.x >> 3);
  const int gn  = N / BNT;
  const int bm  = (swz / gn) * BMT;
  const int bn  = (swz % gn) * BNT;

  const bf16* Ab = A + (size_t)bm * K;
  const bf16* Bb = B + (size_t)bn * K;

  const int NT = K / BKT;   // 112 (even)

  // staging: one wave-instr = 64 lanes x 16B = 1KB = 16 rows of 64B.
  // lane l: row-in-16 = l>>2, slot = l&3; source slot pre-swizzled
  // (l&3)^((l>>2)&3)  (row&3 == (l>>2)&3 since bases are multiples of 16).
  const int srw = lane >> 2;    // 0..15
  const int ssl = lane & 3;

  auto stage16 = [&](const bf16* gpanel, int kt, bf16* ldst, int rbase) {
    const int r  = rbase + wave * 16 + srw;           // tile-local row
    const int sg = ssl ^ (srw & 3);                   // pre-swizzled source slot
    const bf16* src = gpanel + (size_t)r * K + (size_t)kt * BKT + sg * 8;
    __builtin_amdgcn_global_load_lds(
        (const __attribute__((address_space(1))) void*)src,
        (__attribute__((address_space(3))) void*)(ldst + (size_t)(rbase + wave * 16) * BKT),
        16, 0, 0);
  };
  auto stageTile = [&](int kt, int buf) {   // whole tile: A 2 + B 2 instrs
    if (kt >= NT) return;
    stage16(Ab, kt, &sA[buf][0][0], 0);  stage16(Ab, kt, &sA[buf][0][0], 128);
    stage16(Bb, kt, &sB[buf][0][0], 0);  stage16(Bb, kt, &sB[buf][0][0], 128);
  };

  f32x4 acc[8][4];
#pragma unroll
  for (int i = 0; i < 8; ++i)
#pragma unroll
    for (int j = 0; j < 4; ++j)
      acc[i][j] = (f32x4){0.f, 0.f, 0.f, 0.f};

  bf16x8 bfr[4];      // B frags (read at ph0, live both phases)
  bf16x8 afr[4];      // A frags for the current phase (4 m-frags)

  auto loadA = [&](int buf, int half) {   // half 0: m0-3, half 1: m4-7
#pragma unroll
    for (int i = 0; i < 4; ++i) {
      const int R  = wm * 128 + half * 64 + i * 16 + fr;
      const int sp = ks ^ sx;
      afr[i] = *(const bf16x8*)&sA[buf][R][sp * 8];
    }
  };
  auto loadB = [&](int buf) {
#pragma unroll
    for (int j = 0; j < 4; ++j) {
      const int R  = wn * 64 + j * 16 + fr;
      const int sp = ks ^ sx;
      bfr[j] = *(const bf16x8*)&sB[buf][R][sp * 8];
    }
  };
  auto domfma = [&](int half) {
#pragma unroll
    for (int i = 0; i < 4; ++i)
#pragma unroll
      for (int j = 0; j < 4; ++j)
        acc[half * 4 + i][j] = __builtin_amdgcn_mfma_f32_16x16x32_bf16(
            afr[i], bfr[j], acc[half * 4 + i][j], 0, 0, 0);
  };

  // prologue: tile0 staged and drained
  stageTile(0, 0);
  VMW(0);
  BARRIER();

  for (int it = 0; it < NT / 2; ++it) {
#pragma unroll
    for (int u = 0; u < 2; ++u) {
      const int kt = 2 * it + u;
      // ---- phase 0: B + A m0-3; stage whole next tile ----
      loadB(u);
      loadA(u, 0);
      stageTile(kt + 1, u ^ 1);
      BARRIER();
      __builtin_amdgcn_s_setprio(1);
      domfma(0);
      __builtin_amdgcn_s_setprio(0);
      BARRIER();
      // ---- phase 1: A m4-7 ----
      loadA(u, 1);
      BARRIER();
      __builtin_amdgcn_s_setprio(1);
      domfma(1);
      __builtin_amdgcn_s_setprio(0);
      VMW(0);   // next tile fully landed (4 stages, ~1.5-2 phase cover);
                // sibling block fills this drain stall (2 blocks/CU)
      BARRIER();
    }
  }

  // epilogue: C/D layout col = lane&15, row = 4*(lane>>4) + reg
#pragma unroll
  for (int f = 0; f < 8; ++f) {
    const int rb = bm + wm * 128 + f * 16 + ks * 4;
#pragma unroll
    for (int j = 0; j < 4; ++j) {
      const int col = bn + wn * 64 + j * 16 + fr;
#pragma unroll
      for (int r = 0; r < 4; ++r) {
        const int row = rb + r;
        float v = acc[f][j][r];
        if (MODE == 0) v += aux[col];
        else           v += aux[(size_t)row * N + col];
        stv(&C[(size_t)row * N + col], v);
      }
    }
  }
}

// ---------------- launch ----------------
extern "C" void kernel_launch(void* const* d_in, const int* in_sizes, int n_in,
                              void* d_out, int out_size, void* d_ws, size_t ws_size,
                              hipStream_t stream) {
  (void)in_sizes; (void)n_in; (void)out_size; (void)ws_size;
  const float* x    = (const float*)d_in[0];
  const int*   pos  = (const int*)d_in[1];
  const float* ln_w = (const float*)d_in[2];
  const float* Wq   = (const float*)d_in[3];
  const float* bq   = (const float*)d_in[4];
  const float* Wo   = (const float*)d_in[9];
  float* out = (float*)d_out;

  char* ws = (char*)d_ws;
  size_t off = 0;
  bf16* h    = (bf16*)(ws + off); off += (size_t)NTOK * HIDDEN * sizeof(bf16);
  bf16* q    = (bf16*)(ws + off); off += (size_t)NTOK * NQ * sizeof(bf16);
  bf16* Wqb  = (bf16*)(ws + off); off += (size_t)NQ * HIDDEN * sizeof(bf16);
  bf16* Wob  = (bf16*)(ws + off); off += (size_t)HIDDEN * NQ * sizeof(bf16);
  float2* tab = (float2*)(ws + off); off += (size_t)NTOK * NPAIR * sizeof(float2);

  const int n4 = NQ * HIDDEN / 4;
  cvt_f32_bf16<<<(n4 + 255) / 256, 256, 0, stream>>>(Wq, Wqb, n4);
  cvt_f32_bf16<<<(n4 + 255) / 256, 256, 0, stream>>>(Wo, Wob, n4);
  rmsnorm_k<<<NTOK, 256, 0, stream>>>(x, ln_w, h);
  rope_tab_k<<<(NTOK * NPAIR) / 256, 256, 0, stream>>>(pos, tab);

  const int nblk = (NTOK / BMT) * (NQ / BNT);   // 32 * 14 = 448 (%8 == 0)
  gemm256<0, bf16><<<nblk, 512, 0, stream>>>(h, Wqb, bq, q, NTOK, NQ, HIDDEN);
  rope_apply_k<<<NTOK, 256, 0, stream>>>(q, tab);
  gemm256<1, float><<<nblk, 512, 0, stream>>>(q, Wob, x, out, NTOK, HIDDEN, NQ);
}

// Round 15
// 496.354 us; speedup vs baseline: 6.9659x; 6.9659x over previous
//
#include <hip/hip_runtime.h>
#include <hip/hip_bf16.h>

// Qwen2 decoder-layer fragment (Q path only — K/V are dead downstream):
//   h = rmsnorm(x, ln_w); q = h@Wq^T + bq; q = rope(q, pos); out = q@Wo^T + x
// out fp32 [8192, 3584].
// R15 = revert to R9 (best verified: 496 us total, 250 us/GEMM, 842 TF).
// R14's 2-blocks/CU 256^2 attempt was VGPR-infeasible (128-cap -> acc spill,
// 3.2GB scratch fetch). Structure space audit in session log; R9 is the
// plateau of this structure family.

#define HIDDEN   3584
#define NQ       3584
#define NTOK     8192
#define NPAIR    64
#define EPSV     1e-6f

typedef __hip_bfloat16 bf16;
typedef __bf16 bf16x8 __attribute__((ext_vector_type(8)));
typedef float  f32x4  __attribute__((ext_vector_type(4)));

static __device__ __forceinline__ unsigned short f2bu(float f) {
  bf16 h = __float2bfloat16(f);
  return __builtin_bit_cast(unsigned short, h);
}
static __device__ __forceinline__ void stv(float* p, float v) { *p = v; }
static __device__ __forceinline__ void stv(bf16* p, float v) { *p = __float2bfloat16(v); }

// ---------------- fp32 -> bf16 weight conversion ----------------
__global__ __launch_bounds__(256)
void cvt_f32_bf16(const float* __restrict__ s, bf16* __restrict__ d, int n4) {
  int i = blockIdx.x * 256 + threadIdx.x;
  if (i >= n4) return;
  float4 f = ((const float4*)s)[i];
  ushort4 o;
  o.x = f2bu(f.x); o.y = f2bu(f.y); o.z = f2bu(f.z); o.w = f2bu(f.w);
  ((ushort4*)d)[i] = o;
}

// ---------------- RMSNorm: x fp32 [row, 3584] -> h bf16 ----------------
__global__ __launch_bounds__(256)
void rmsnorm_k(const float* __restrict__ x, const float* __restrict__ w,
               bf16* __restrict__ h) {
  const int row = blockIdx.x;
  const int t = threadIdx.x;
  const float4* xr = (const float4*)(x + (size_t)row * HIDDEN);
  const float4* wr = (const float4*)w;

  float4 v0 = xr[t], v1 = xr[t + 256], v2 = xr[t + 512];
  float4 v3 = make_float4(0.f, 0.f, 0.f, 0.f);
  if (t < 128) v3 = xr[t + 768];

  float ss = v0.x*v0.x + v0.y*v0.y + v0.z*v0.z + v0.w*v0.w
           + v1.x*v1.x + v1.y*v1.y + v1.z*v1.z + v1.w*v1.w
           + v2.x*v2.x + v2.y*v2.y + v2.z*v2.z + v2.w*v2.w
           + v3.x*v3.x + v3.y*v3.y + v3.z*v3.z + v3.w*v3.w;

#pragma unroll
  for (int off = 32; off > 0; off >>= 1) ss += __shfl_down(ss, off);
  __shared__ float red[4];
  if ((t & 63) == 0) red[t >> 6] = ss;
  __syncthreads();
  float tot = red[0] + red[1] + red[2] + red[3];
  float scale = rsqrtf(tot * (1.0f / HIDDEN) + EPSV);

  ushort4* hr = (ushort4*)(h + (size_t)row * HIDDEN);
  float4 w0 = wr[t], w1 = wr[t + 256], w2 = wr[t + 512];
  ushort4 o;
  o.x = f2bu(v0.x*scale*w0.x); o.y = f2bu(v0.y*scale*w0.y);
  o.z = f2bu(v0.z*scale*w0.z); o.w = f2bu(v0.w*scale*w0.w);
  hr[t] = o;
  o.x = f2bu(v1.x*scale*w1.x); o.y = f2bu(v1.y*scale*w1.y);
  o.z = f2bu(v1.z*scale*w1.z); o.w = f2bu(v1.w*scale*w1.w);
  hr[t + 256] = o;
  o.x = f2bu(v2.x*scale*w2.x); o.y = f2bu(v2.y*scale*w2.y);
  o.z = f2bu(v2.z*scale*w2.z); o.w = f2bu(v2.w*scale*w2.w);
  hr[t + 512] = o;
  if (t < 128) {
    float4 w3 = wr[t + 768];
    o.x = f2bu(v3.x*scale*w3.x); o.y = f2bu(v3.y*scale*w3.y);
    o.z = f2bu(v3.z*scale*w3.z); o.w = f2bu(v3.w*scale*w3.w);
    hr[t + 768] = o;
  }
}

// ---------------- per-token rope table ----------------
__global__ __launch_bounds__(256)
void rope_tab_k(const int* __restrict__ pos, float2* __restrict__ tab) {
  int idx = blockIdx.x * 256 + threadIdx.x;   // NTOK*64
  int t = idx >> 6;
  int i = idx & 63;
  float inv = exp2f(-(float)i * (19.931568569324174f / 64.0f));
  float ang = (float)pos[t] * inv;
  float s, c;
  sincosf(ang, &s, &c);
  tab[idx] = make_float2(c, s);
}

// ---------------- in-place neox rope on q bf16 [NTOK, 28, 128] ----------------
__global__ __launch_bounds__(256)
void rope_apply_k(bf16* __restrict__ q, const float2* __restrict__ tab) {
  const int t = blockIdx.x;
  bf16* qt = q + (size_t)t * NQ;
  const float2* tb = tab + (size_t)t * NPAIR;
  for (int j = threadIdx.x; j < 28 * NPAIR; j += 256) {
    int head = j >> 6;
    int i = j & 63;
    float2 cs = tb[i];
    int base = head * 128 + i;
    float x1 = __bfloat162float(qt[base]);
    float x2 = __bfloat162float(qt[base + 64]);
    qt[base]      = __float2bfloat16(x1 * cs.x - x2 * cs.y);
    qt[base + 64] = __float2bfloat16(x2 * cs.x + x1 * cs.y);
  }
}

// ================= 256x256 8-phase bf16 GEMM (C = A * B^T) ==================
// 8 waves (2M x 4N), BK=64 K-tiles, double-buffered LDS (128 KiB).
// Soft barriers (__builtin_amdgcn_s_barrier, no LLVM memory clobber); only
// the counted VMW() asm (volatile + memory clobber) orders memory.
// MFMA shape: 16x16x32. Swizzle: slot' = slot ^ (row & 7) (involution;
// conflict-free, R5-verified: SQ_LDS_BANK_CONFLICT == 0). gload_lds dest
// linear, source pre-swizzled, ds_read swizzled.
// Stage stagger (tile T_t -> buf t&1; B dead after its q0, AH0 after q1,
// AH1 after q3): ph0:T1.AH1 ph1:T2.Blo ph2:T2.Bhi ph3:T2.AH0 ph4:T2.AH1
//                ph5:T3.Blo ph6:T3.Bhi ph7:T3.AH0
// vmcnt ledger (2 instr/stage, queue-verified): end-ph3 VMW(6) -> prev
// ph5,6,7 + this ph0 landed (guards ph4/ph6 reads); end-ph7 VMW(6) -> this
// ph1,2,3,4 landed (guards next ph0/ph2 reads).
// Last iter (stages skipped): end-ph3 VMW(2), end-ph5 VMW(0).
#define BMT 256
#define BNT 256
#define BKT 64

#define BARRIER() __builtin_amdgcn_s_barrier()
#define VMW(n)    asm volatile("s_waitcnt vmcnt(" #n ")" ::: "memory")

template <int MODE, typename OutT>   // MODE 0: +bias[col] -> OutT; MODE 1: +resid[row,col]
__global__ __launch_bounds__(512, 2)
void gemm256(const bf16* __restrict__ A, const bf16* __restrict__ B,
             const float* __restrict__ aux, OutT* __restrict__ C,
             int M, int N, int K) {
  __shared__ __align__(16) bf16 sA[2][BMT][BKT];   // 64 KiB
  __shared__ __align__(16) bf16 sB[2][BNT][BKT];   // 64 KiB

  const int tid  = threadIdx.x;
  const int wave = tid >> 6;     // 0..7
  const int lane = tid & 63;
  const int wm   = wave >> 2;    // 0..1
  const int wn   = wave & 3;     // 0..3
  const int fr   = lane & 15;
  const int ks   = lane >> 4;
  const int sx   = fr & 7;       // read-side slot XOR = row & 7

  // bijective XCD swizzle, bn-fast within an XCD (A panel hot in XCD L2)
  const int nwg = gridDim.x;           // 448, % 8 == 0
  const int cpx = nwg >> 3;
  const int swz = (blockIdx.x & 7) * cpx + (blockIdx.x >> 3);
  const int gn  = N / BNT;
  const int bm  = (swz / gn) * BMT;
  const int bn  = (swz % gn) * BNT;

  const bf16* Ab = A + (size_t)bm * K;
  const bf16* Bb = B + (size_t)bn * K;

  const int NT = K / BKT;   // 56 (even)

  // staging: one 64-row chunk (8KB): wave w rows [rbase+w*8,+8);
  // lane: row = l>>3, slot = l&7; source pre-swizzled slot = (l&7)^(row&7)
  const int srw = lane >> 3;    // 0..7  (== row&7)
  const int ssl = lane & 7;

  auto stage64 = [&](const bf16* gpanel, int kt, bf16* ldst, int rbase) {
    const int r  = rbase + wave * 8 + srw;            // tile-local row
    const int sg = ssl ^ srw;                         // pre-swizzled source slot
    const bf16* src = gpanel + (size_t)r * K + (size_t)kt * BKT + sg * 8;
    __builtin_amdgcn_global_load_lds(
        (const __attribute__((address_space(1))) void*)src,
        (__attribute__((address_space(3))) void*)(ldst + (size_t)(wave * 8) * BKT),
        16, 0, 0);
  };
  // kinds: 0=A_H0{0,128}, 1=A_H1{64,192}, 2=B_lo{0,64}, 3=B_hi{128,192}
  auto stage16k = [&](int kind, int buf, int kt) {
    if (kt >= NT) return;
    if (kind == 0)      { stage64(Ab, kt, &sA[buf][0][0],   0);   stage64(Ab, kt, &sA[buf][128][0], 128); }
    else if (kind == 1) { stage64(Ab, kt, &sA[buf][64][0],  64);  stage64(Ab, kt, &sA[buf][192][0], 192); }
    else if (kind == 2) { stage64(Bb, kt, &sB[buf][0][0],   0);   stage64(Bb, kt, &sB[buf][64][0],  64); }
    else                { stage64(Bb, kt, &sB[buf][128][0], 128); stage64(Bb, kt, &sB[buf][192][0], 192); }
  };

  f32x4 acc[8][4];
#pragma unroll
  for (int i = 0; i < 8; ++i)
#pragma unroll
    for (int j = 0; j < 4; ++j)
      acc[i][j] = (f32x4){0.f, 0.f, 0.f, 0.f};

  bf16x8 bfr[4][2];       // B frags, whole tile (loaded at q0, live q0-q3)
  bf16x8 afr[2][2];       // A frags for the current phase

  auto loadA = [&](int buf, int qq) {
#pragma unroll
    for (int i = 0; i < 2; ++i)
#pragma unroll
      for (int kk = 0; kk < 2; ++kk) {
        const int R  = wm * 128 + qq * 32 + i * 16 + fr;
        const int sp = (kk * 4 + ks) ^ sx;
        afr[i][kk] = *(const bf16x8*)&sA[buf][R][sp * 8];
      }
  };
  auto loadB = [&](int buf) {
#pragma unroll
    for (int j = 0; j < 4; ++j)
#pragma unroll
      for (int kk = 0; kk < 2; ++kk) {
        const int R  = wn * 64 + j * 16 + fr;
        const int sp = (kk * 4 + ks) ^ sx;
        bfr[j][kk] = *(const bf16x8*)&sB[buf][R][sp * 8];
      }
  };
  auto domfma = [&](int q) {
#pragma unroll
    for (int i = 0; i < 2; ++i)
#pragma unroll
      for (int j = 0; j < 4; ++j)
#pragma unroll
        for (int kk = 0; kk < 2; ++kk)
          acc[q * 2 + i][j] = __builtin_amdgcn_mfma_f32_16x16x32_bf16(
              afr[i][kk], bfr[j][kk], acc[q * 2 + i][j], 0, 0, 0);
  };

  // prologue: tile0 complete (8 instr/wave), tile1 B + A_H0 (6 instr/wave)
  stage16k(2, 0, 0); stage16k(3, 0, 0); stage16k(0, 0, 0); stage16k(1, 0, 0);
  stage16k(2, 1, 1); stage16k(3, 1, 1); stage16k(0, 1, 1);
  VMW(6);   // tile0 fully landed
  BARRIER();

  const int nit = NT / 2;   // 28

  for (int it = 0; it < nit; ++it) {
    const bool last = (it == nit - 1);
#pragma unroll
    for (int u = 0; u < 2; ++u) {          // tile kt = 2*it+u, buf u
#pragma unroll
      for (int q = 0; q < 4; ++q) {        // phase within tile
        const int ph = u * 4 + q;
        // ---- ds_read this phase's fragments (compiler-managed waits) ----
        loadA(u, q);
        if (q == 0) loadB(u);
        // ---- staggered 16KB stage (targets proven-dead regions) ----
        if (ph == 0)      stage16k(1, 1, 2 * it + 1);   // A_H1 of tile 2it+1
        else if (ph == 1) stage16k(2, 0, 2 * it + 2);   // B_lo  tile 2it+2
        else if (ph == 2) stage16k(3, 0, 2 * it + 2);   // B_hi
        else if (ph == 3) stage16k(0, 0, 2 * it + 2);   // A_H0
        else if (ph == 4) stage16k(1, 0, 2 * it + 2);   // A_H1
        else if (ph == 5) stage16k(2, 1, 2 * it + 3);   // B_lo  tile 2it+3
        else if (ph == 6) stage16k(3, 1, 2 * it + 3);   // B_hi
        else              stage16k(0, 1, 2 * it + 3);   // A_H0
        BARRIER();
        __builtin_amdgcn_s_setprio(1);
        domfma(q);
        __builtin_amdgcn_s_setprio(0);
        // ---- counted vmcnt waits (ledger in header comment) ----
        if (ph == 3) {
          if (!last) { VMW(6); } else { VMW(2); }
        } else if (ph == 5) {
          if (last)  { VMW(0); }
        } else if (ph == 7) {
          if (!last) { VMW(6); }
        }
        BARRIER();
      }
    }
  }

  // epilogue: C/D layout col = lane&15, row = 4*(lane>>4) + reg
#pragma unroll
  for (int f = 0; f < 8; ++f) {
    const int rb = bm + wm * 128 + f * 16 + ks * 4;
#pragma unroll
    for (int j = 0; j < 4; ++j) {
      const int col = bn + wn * 64 + j * 16 + fr;
#pragma unroll
      for (int r = 0; r < 4; ++r) {
        const int row = rb + r;
        float v = acc[f][j][r];
        if (MODE == 0) v += aux[col];
        else           v += aux[(size_t)row * N + col];
        stv(&C[(size_t)row * N + col], v);
      }
    }
  }
}

// ---------------- launch ----------------
extern "C" void kernel_launch(void* const* d_in, const int* in_sizes, int n_in,
                              void* d_out, int out_size, void* d_ws, size_t ws_size,
                              hipStream_t stream) {
  (void)in_sizes; (void)n_in; (void)out_size; (void)ws_size;
  const float* x    = (const float*)d_in[0];
  const int*   pos  = (const int*)d_in[1];
  const float* ln_w = (const float*)d_in[2];
  const float* Wq   = (const float*)d_in[3];
  const float* bq   = (const float*)d_in[4];
  const float* Wo   = (const float*)d_in[9];
  float* out = (float*)d_out;

  char* ws = (char*)d_ws;
  size_t off = 0;
  bf16* h    = (bf16*)(ws + off); off += (size_t)NTOK * HIDDEN * sizeof(bf16);
  bf16* q    = (bf16*)(ws + off); off += (size_t)NTOK * NQ * sizeof(bf16);
  bf16* Wqb  = (bf16*)(ws + off); off += (size_t)NQ * HIDDEN * sizeof(bf16);
  bf16* Wob  = (bf16*)(ws + off); off += (size_t)HIDDEN * NQ * sizeof(bf16);
  float2* tab = (float2*)(ws + off); off += (size_t)NTOK * NPAIR * sizeof(float2);

  const int n4 = NQ * HIDDEN / 4;
  cvt_f32_bf16<<<(n4 + 255) / 256, 256, 0, stream>>>(Wq, Wqb, n4);
  cvt_f32_bf16<<<(n4 + 255) / 256, 256, 0, stream>>>(Wo, Wob, n4);
  rmsnorm_k<<<NTOK, 256, 0, stream>>>(x, ln_w, h);
  rope_tab_k<<<(NTOK * NPAIR) / 256, 256, 0, stream>>>(pos, tab);

  const int nblk = (NTOK / BMT) * (NQ / BNT);   // 32 * 14 = 448 (%8 == 0)
  gemm256<0, bf16><<<nblk, 512, 0, stream>>>(h, Wqb, bq, q, NTOK, NQ, HIDDEN);
  rope_apply_k<<<NTOK, 256, 0, stream>>>(q, tab);
  gemm256<1, float><<<nblk, 512, 0, stream>>>(q, Wob, x, out, NTOK, HIDDEN, NQ);
}

// Round 16
// 485.502 us; speedup vs baseline: 7.1216x; 1.0224x over previous
//
#include <hip/hip_runtime.h>
#include <hip/hip_bf16.h>

// Qwen2 decoder-layer fragment (Q path only — K/V are dead downstream):
//   h = rmsnorm(x, ln_w); q = rope(h@Wq^T + bq); out = q@Wo^T + x
// out fp32 [8192, 3584].
// R16 = R9 GEMM core (best verified: 250 us/GEMM) + RoPE fused into GEMM1's
// epilogue via pair-local wave->column remap (nmap), rope_apply kernel
// removed, cvt launches merged. K-loop schedule/staging/ledger untouched.

#define HIDDEN   3584
#define NQ       3584
#define NTOK     8192
#define NPAIR    64
#define EPSV     1e-6f

typedef __hip_bfloat16 bf16;
typedef __bf16 bf16x8 __attribute__((ext_vector_type(8)));
typedef float  f32x4  __attribute__((ext_vector_type(4)));

static __device__ __forceinline__ unsigned short f2bu(float f) {
  bf16 h = __float2bfloat16(f);
  return __builtin_bit_cast(unsigned short, h);
}
static __device__ __forceinline__ void stv(float* p, float v) { *p = v; }
static __device__ __forceinline__ void stv(bf16* p, float v) { *p = __float2bfloat16(v); }

// ---------------- fp32 -> bf16 weight conversion (both weights, 1 launch) ---
__global__ __launch_bounds__(256)
void cvt2_f32_bf16(const float* __restrict__ s1, bf16* __restrict__ d1,
                   const float* __restrict__ s2, bf16* __restrict__ d2, int n4) {
  int i = blockIdx.x * 256 + threadIdx.x;
  const float* s; bf16* d;
  if (i < n4)           { s = s1; d = d1; }
  else if (i < 2 * n4)  { s = s2; d = d2; i -= n4; }
  else return;
  float4 f = ((const float4*)s)[i];
  ushort4 o;
  o.x = f2bu(f.x); o.y = f2bu(f.y); o.z = f2bu(f.z); o.w = f2bu(f.w);
  ((ushort4*)d)[i] = o;
}

// ---------------- RMSNorm: x fp32 [row, 3584] -> h bf16 ----------------
__global__ __launch_bounds__(256)
void rmsnorm_k(const float* __restrict__ x, const float* __restrict__ w,
               bf16* __restrict__ h) {
  const int row = blockIdx.x;
  const int t = threadIdx.x;
  const float4* xr = (const float4*)(x + (size_t)row * HIDDEN);
  const float4* wr = (const float4*)w;

  float4 v0 = xr[t], v1 = xr[t + 256], v2 = xr[t + 512];
  float4 v3 = make_float4(0.f, 0.f, 0.f, 0.f);
  if (t < 128) v3 = xr[t + 768];

  float ss = v0.x*v0.x + v0.y*v0.y + v0.z*v0.z + v0.w*v0.w
           + v1.x*v1.x + v1.y*v1.y + v1.z*v1.z + v1.w*v1.w
           + v2.x*v2.x + v2.y*v2.y + v2.z*v2.z + v2.w*v2.w
           + v3.x*v3.x + v3.y*v3.y + v3.z*v3.z + v3.w*v3.w;

#pragma unroll
  for (int off = 32; off > 0; off >>= 1) ss += __shfl_down(ss, off);
  __shared__ float red[4];
  if ((t & 63) == 0) red[t >> 6] = ss;
  __syncthreads();
  float tot = red[0] + red[1] + red[2] + red[3];
  float scale = rsqrtf(tot * (1.0f / HIDDEN) + EPSV);

  ushort4* hr = (ushort4*)(h + (size_t)row * HIDDEN);
  float4 w0 = wr[t], w1 = wr[t + 256], w2 = wr[t + 512];
  ushort4 o;
  o.x = f2bu(v0.x*scale*w0.x); o.y = f2bu(v0.y*scale*w0.y);
  o.z = f2bu(v0.z*scale*w0.z); o.w = f2bu(v0.w*scale*w0.w);
  hr[t] = o;
  o.x = f2bu(v1.x*scale*w1.x); o.y = f2bu(v1.y*scale*w1.y);
  o.z = f2bu(v1.z*scale*w1.z); o.w = f2bu(v1.w*scale*w1.w);
  hr[t + 256] = o;
  o.x = f2bu(v2.x*scale*w2.x); o.y = f2bu(v2.y*scale*w2.y);
  o.z = f2bu(v2.z*scale*w2.z); o.w = f2bu(v2.w*scale*w2.w);
  hr[t + 512] = o;
  if (t < 128) {
    float4 w3 = wr[t + 768];
    o.x = f2bu(v3.x*scale*w3.x); o.y = f2bu(v3.y*scale*w3.y);
    o.z = f2bu(v3.z*scale*w3.z); o.w = f2bu(v3.w*scale*w3.w);
    hr[t + 768] = o;
  }
}

// ---------------- per-token rope table: tab[t][i] = (cos, sin) ----------------
__global__ __launch_bounds__(256)
void rope_tab_k(const int* __restrict__ pos, float2* __restrict__ tab) {
  int idx = blockIdx.x * 256 + threadIdx.x;   // NTOK*64
  int t = idx >> 6;
  int i = idx & 63;
  float inv = exp2f(-(float)i * (19.931568569324174f / 64.0f));
  float ang = (float)pos[t] * inv;
  float s, c;
  sincosf(ang, &s, &c);
  tab[idx] = make_float2(c, s);
}

// ================= 256x256 8-phase bf16 GEMM (C = A * B^T) ==================
// R9-verified core. 8 waves (2M x 4N), BK=64, double-buffered LDS (128 KiB).
// Soft barriers; counted VMW() asm orders memory. 16x16x32 MFMA.
// Swizzle slot' = slot ^ (row&7) (conflict-free, R5: SQ_LDS_BANK_CONFLICT=0).
// Stage stagger + vmcnt ledger identical to R9 (see R15 header comments).
// R16 delta: wave->column remap nmap(j) = (wn>>1)*128 + (wn&1)*32 +
// (j&1)*16 + (j>>1)*64 — bijective on block cols; each thread holds BOTH
// halves (j and j+2) of every rope pair (i, i+64) of a head. MODE 0 epilogue
// applies rope thread-locally in fp32 (x = acc + bias): out[c] = x1*cos -
// x2*sin, out[c+64] = x2*cos + x1*sin, i = (wn&1)*32 + j*16 + fr, t = row.
// MODE 1 uses the same nmap (bijection; no rope).
#define BMT 256
#define BNT 256
#define BKT 64

#define BARRIER() __builtin_amdgcn_s_barrier()
#define VMW(n)    asm volatile("s_waitcnt vmcnt(" #n ")" ::: "memory")

template <int MODE, typename OutT>   // MODE 0: rope(acc+bias[col]) -> OutT; MODE 1: +resid[row,col]
__global__ __launch_bounds__(512, 2)
void gemm256(const bf16* __restrict__ A, const bf16* __restrict__ B,
             const float* __restrict__ aux, const float2* __restrict__ tab,
             OutT* __restrict__ C, int M, int N, int K) {
  __shared__ __align__(16) bf16 sA[2][BMT][BKT];   // 64 KiB
  __shared__ __align__(16) bf16 sB[2][BNT][BKT];   // 64 KiB

  const int tid  = threadIdx.x;
  const int wave = tid >> 6;     // 0..7
  const int lane = tid & 63;
  const int wm   = wave >> 2;    // 0..1
  const int wn   = wave & 3;     // 0..3
  const int fr   = lane & 15;
  const int ks   = lane >> 4;
  const int sx   = fr & 7;       // read-side slot XOR = row & 7

  // pair-local column map: frag j -> block-col base (j and j+2 are a rope pair)
  auto nmap = [&](int j) {
    return (wn >> 1) * 128 + (wn & 1) * 32 + ((j & 1) << 4) + ((j >> 1) << 6);
  };

  // bijective XCD swizzle, bn-fast within an XCD (A panel hot in XCD L2)
  const int nwg = gridDim.x;           // 448, % 8 == 0
  const int cpx = nwg >> 3;
  const int swz = (blockIdx.x & 7) * cpx + (blockIdx.x >> 3);
  const int gn  = N / BNT;
  const int bm  = (swz / gn) * BMT;
  const int bn  = (swz % gn) * BNT;

  const bf16* Ab = A + (size_t)bm * K;
  const bf16* Bb = B + (size_t)bn * K;

  const int NT = K / BKT;   // 56 (even)

  // staging: one 64-row chunk (8KB): wave w rows [rbase+w*8,+8);
  // lane: row = l>>3, slot = l&7; source pre-swizzled slot = (l&7)^(row&7)
  const int srw = lane >> 3;    // 0..7  (== row&7)
  const int ssl = lane & 7;

  auto stage64 = [&](const bf16* gpanel, int kt, bf16* ldst, int rbase) {
    const int r  = rbase + wave * 8 + srw;            // tile-local row
    const int sg = ssl ^ srw;                         // pre-swizzled source slot
    const bf16* src = gpanel + (size_t)r * K + (size_t)kt * BKT + sg * 8;
    __builtin_amdgcn_global_load_lds(
        (const __attribute__((address_space(1))) void*)src,
        (__attribute__((address_space(3))) void*)(ldst + (size_t)(wave * 8) * BKT),
        16, 0, 0);
  };
  // kinds: 0=A_H0{0,128}, 1=A_H1{64,192}, 2=B_lo{0,64}, 3=B_hi{128,192}
  auto stage16k = [&](int kind, int buf, int kt) {
    if (kt >= NT) return;
    if (kind == 0)      { stage64(Ab, kt, &sA[buf][0][0],   0);   stage64(Ab, kt, &sA[buf][128][0], 128); }
    else if (kind == 1) { stage64(Ab, kt, &sA[buf][64][0],  64);  stage64(Ab, kt, &sA[buf][192][0], 192); }
    else if (kind == 2) { stage64(Bb, kt, &sB[buf][0][0],   0);   stage64(Bb, kt, &sB[buf][64][0],  64); }
    else                { stage64(Bb, kt, &sB[buf][128][0], 128); stage64(Bb, kt, &sB[buf][192][0], 192); }
  };

  f32x4 acc[8][4];
#pragma unroll
  for (int i = 0; i < 8; ++i)
#pragma unroll
    for (int j = 0; j < 4; ++j)
      acc[i][j] = (f32x4){0.f, 0.f, 0.f, 0.f};

  bf16x8 bfr[4][2];       // B frags, whole tile (loaded at q0, live q0-q3)
  bf16x8 afr[2][2];       // A frags for the current phase

  auto loadA = [&](int buf, int qq) {
#pragma unroll
    for (int i = 0; i < 2; ++i)
#pragma unroll
      for (int kk = 0; kk < 2; ++kk) {
        const int R  = wm * 128 + qq * 32 + i * 16 + fr;
        const int sp = (kk * 4 + ks) ^ sx;
        afr[i][kk] = *(const bf16x8*)&sA[buf][R][sp * 8];
      }
  };
  auto loadB = [&](int buf) {
#pragma unroll
    for (int j = 0; j < 4; ++j)
#pragma unroll
      for (int kk = 0; kk < 2; ++kk) {
        const int R  = nmap(j) + fr;          // remapped (same conflict algebra)
        const int sp = (kk * 4 + ks) ^ sx;
        bfr[j][kk] = *(const bf16x8*)&sB[buf][R][sp * 8];
      }
  };
  auto domfma = [&](int q) {
#pragma unroll
    for (int i = 0; i < 2; ++i)
#pragma unroll
      for (int j = 0; j < 4; ++j)
#pragma unroll
        for (int kk = 0; kk < 2; ++kk)
          acc[q * 2 + i][j] = __builtin_amdgcn_mfma_f32_16x16x32_bf16(
              afr[i][kk], bfr[j][kk], acc[q * 2 + i][j], 0, 0, 0);
  };

  // prologue: tile0 complete (8 instr/wave), tile1 B + A_H0 (6 instr/wave)
  stage16k(2, 0, 0); stage16k(3, 0, 0); stage16k(0, 0, 0); stage16k(1, 0, 0);
  stage16k(2, 1, 1); stage16k(3, 1, 1); stage16k(0, 1, 1);
  VMW(6);   // tile0 fully landed
  BARRIER();

  const int nit = NT / 2;   // 28

  for (int it = 0; it < nit; ++it) {
    const bool last = (it == nit - 1);
#pragma unroll
    for (int u = 0; u < 2; ++u) {          // tile kt = 2*it+u, buf u
#pragma unroll
      for (int q = 0; q < 4; ++q) {        // phase within tile
        const int ph = u * 4 + q;
        // ---- ds_read this phase's fragments (compiler-managed waits) ----
        loadA(u, q);
        if (q == 0) loadB(u);
        // ---- staggered 16KB stage (targets proven-dead regions) ----
        if (ph == 0)      stage16k(1, 1, 2 * it + 1);   // A_H1 of tile 2it+1
        else if (ph == 1) stage16k(2, 0, 2 * it + 2);   // B_lo  tile 2it+2
        else if (ph == 2) stage16k(3, 0, 2 * it + 2);   // B_hi
        else if (ph == 3) stage16k(0, 0, 2 * it + 2);   // A_H0
        else if (ph == 4) stage16k(1, 0, 2 * it + 2);   // A_H1
        else if (ph == 5) stage16k(2, 1, 2 * it + 3);   // B_lo  tile 2it+3
        else if (ph == 6) stage16k(3, 1, 2 * it + 3);   // B_hi
        else              stage16k(0, 1, 2 * it + 3);   // A_H0
        BARRIER();
        __builtin_amdgcn_s_setprio(1);
        domfma(q);
        __builtin_amdgcn_s_setprio(0);
        // ---- counted vmcnt waits (R9 ledger) ----
        if (ph == 3) {
          if (!last) { VMW(6); } else { VMW(2); }
        } else if (ph == 5) {
          if (last)  { VMW(0); }
        } else if (ph == 7) {
          if (!last) { VMW(6); }
        }
        BARRIER();
      }
    }
  }

  // epilogue: C/D layout col-in-frag = lane&15 (fr), row = 4*(lane>>4) + reg
  if (MODE == 0) {
    // fused rope: frag pair (j, j+2) = cols (c, c+64) of one head
#pragma unroll
    for (int f = 0; f < 8; ++f) {
      const int rb = bm + wm * 128 + f * 16 + ks * 4;
#pragma unroll
      for (int j = 0; j < 2; ++j) {
        const int i_idx = (wn & 1) * 32 + j * 16 + fr;   // pair index in [0,64)
        const int c1 = bn + nmap(j) + fr;
        const int c2 = c1 + 64;
        const float b1 = aux[c1], b2 = aux[c2];
#pragma unroll
        for (int r = 0; r < 4; ++r) {
          const int row = rb + r;                        // token id
          const float2 cs = tab[(size_t)row * NPAIR + i_idx];
          const float x1 = acc[f][j][r]     + b1;
          const float x2 = acc[f][j + 2][r] + b2;
          stv(&C[(size_t)row * N + c1], x1 * cs.x - x2 * cs.y);
          stv(&C[(size_t)row * N + c2], x2 * cs.x + x1 * cs.y);
        }
      }
    }
  } else {
#pragma unroll
    for (int f = 0; f < 8; ++f) {
      const int rb = bm + wm * 128 + f * 16 + ks * 4;
#pragma unroll
      for (int j = 0; j < 4; ++j) {
        const int col = bn + nmap(j) + fr;
#pragma unroll
        for (int r = 0; r < 4; ++r) {
          const int row = rb + r;
          stv(&C[(size_t)row * N + col],
              acc[f][j][r] + aux[(size_t)row * N + col]);
        }
      }
    }
  }
}

// ---------------- launch ----------------
extern "C" void kernel_launch(void* const* d_in, const int* in_sizes, int n_in,
                              void* d_out, int out_size, void* d_ws, size_t ws_size,
                              hipStream_t stream) {
  (void)in_sizes; (void)n_in; (void)out_size; (void)ws_size;
  const float* x    = (const float*)d_in[0];
  const int*   pos  = (const int*)d_in[1];
  const float* ln_w = (const float*)d_in[2];
  const float* Wq   = (const float*)d_in[3];
  const float* bq   = (const float*)d_in[4];
  const float* Wo   = (const float*)d_in[9];
  float* out = (float*)d_out;

  char* ws = (char*)d_ws;
  size_t off = 0;
  bf16* h    = (bf16*)(ws + off); off += (size_t)NTOK * HIDDEN * sizeof(bf16);
  bf16* q    = (bf16*)(ws + off); off += (size_t)NTOK * NQ * sizeof(bf16);
  bf16* Wqb  = (bf16*)(ws + off); off += (size_t)NQ * HIDDEN * sizeof(bf16);
  bf16* Wob  = (bf16*)(ws + off); off += (size_t)HIDDEN * NQ * sizeof(bf16);
  float2* tab = (float2*)(ws + off); off += (size_t)NTOK * NPAIR * sizeof(float2);

  const int n4 = NQ * HIDDEN / 4;
  cvt2_f32_bf16<<<(2 * n4 + 255) / 256, 256, 0, stream>>>(Wq, Wqb, Wo, Wob, n4);
  rmsnorm_k<<<NTOK, 256, 0, stream>>>(x, ln_w, h);
  rope_tab_k<<<(NTOK * NPAIR) / 256, 256, 0, stream>>>(pos, tab);

  const int nblk = (NTOK / BMT) * (NQ / BNT);   // 32 * 14 = 448 (%8 == 0)
  gemm256<0, bf16><<<nblk, 512, 0, stream>>>(h, Wqb, bq, tab, q, NTOK, NQ, HIDDEN);
  gemm256<1, float><<<nblk, 512, 0, stream>>>(q, Wob, x, nullptr, out, NTOK, HIDDEN, NQ);
}

// Round 17
// 480.553 us; speedup vs baseline: 7.1949x; 1.0103x over previous
//
#include <hip/hip_runtime.h>
#include <hip/hip_bf16.h>

// Qwen2 decoder-layer fragment (Q path only — K/V are dead downstream):
//   h = rmsnorm(x, ln_w); q = rope(h@Wq^T + bq); out = q@Wo^T + x
// out fp32 [8192, 3584].
// R17 = R16 (best verified: 485.5 us) + side kernels (cvt2 / rmsnorm /
// rope_tab) fused into ONE grid-sectioned prep kernel (independent ops,
// disjoint outputs; removes 2 launches + serialization gaps). GEMMs
// byte-identical to R16.

#define HIDDEN   3584
#define NQ       3584
#define NTOK     8192
#define NPAIR    64
#define EPSV     1e-6f

typedef __hip_bfloat16 bf16;
typedef __bf16 bf16x8 __attribute__((ext_vector_type(8)));
typedef float  f32x4  __attribute__((ext_vector_type(4)));

static __device__ __forceinline__ unsigned short f2bu(float f) {
  bf16 h = __float2bfloat16(f);
  return __builtin_bit_cast(unsigned short, h);
}
static __device__ __forceinline__ void stv(float* p, float v) { *p = v; }
static __device__ __forceinline__ void stv(bf16* p, float v) { *p = __float2bfloat16(v); }

// ============ fused prep: weight cvt + rmsnorm + rope table =================
// grid sections (all 256-thread blocks):
//   [0, NCVT)            : fp32->bf16 cvt of Wq then Wo (float4 granularity)
//   [NCVT, NCVT+NTOK)    : rmsnorm row (block-per-row, R2-verified body)
//   [NCVT+NTOK, +NTAB)   : rope cos/sin table
#define N4W   (NQ * HIDDEN / 4)          // 3,211,264 float4s per weight
#define NCVT  (2 * N4W / 256)            // 25088 blocks
#define NTAB  (NTOK * NPAIR / 256)       // 2048 blocks

__global__ __launch_bounds__(256)
void prep_k(const float* __restrict__ Wq, bf16* __restrict__ Wqb,
            const float* __restrict__ Wo, bf16* __restrict__ Wob,
            const float* __restrict__ x, const float* __restrict__ w,
            bf16* __restrict__ h,
            const int* __restrict__ pos, float2* __restrict__ tab) {
  const int blk = blockIdx.x;
  const int t = threadIdx.x;

  if (blk < NCVT) {
    // ---- weight conversion ----
    int i = blk * 256 + t;                 // index into 2*N4W float4s
    const float* s; bf16* d;
    if (i < N4W) { s = Wq; d = Wqb; }
    else         { s = Wo; d = Wob; i -= N4W; }
    float4 f = ((const float4*)s)[i];
    ushort4 o;
    o.x = f2bu(f.x); o.y = f2bu(f.y); o.z = f2bu(f.z); o.w = f2bu(f.w);
    ((ushort4*)d)[i] = o;
    return;
  }

  if (blk < NCVT + NTOK) {
    // ---- rmsnorm row ----
    const int row = blk - NCVT;
    const float4* xr = (const float4*)(x + (size_t)row * HIDDEN);
    const float4* wr = (const float4*)w;

    float4 v0 = xr[t], v1 = xr[t + 256], v2 = xr[t + 512];
    float4 v3 = make_float4(0.f, 0.f, 0.f, 0.f);
    if (t < 128) v3 = xr[t + 768];

    float ss = v0.x*v0.x + v0.y*v0.y + v0.z*v0.z + v0.w*v0.w
             + v1.x*v1.x + v1.y*v1.y + v1.z*v1.z + v1.w*v1.w
             + v2.x*v2.x + v2.y*v2.y + v2.z*v2.z + v2.w*v2.w
             + v3.x*v3.x + v3.y*v3.y + v3.z*v3.z + v3.w*v3.w;

#pragma unroll
    for (int off = 32; off > 0; off >>= 1) ss += __shfl_down(ss, off);
    __shared__ float red[4];
    if ((t & 63) == 0) red[t >> 6] = ss;
    __syncthreads();
    float tot = red[0] + red[1] + red[2] + red[3];
    float scale = rsqrtf(tot * (1.0f / HIDDEN) + EPSV);

    ushort4* hr = (ushort4*)(h + (size_t)row * HIDDEN);
    float4 w0 = wr[t], w1 = wr[t + 256], w2 = wr[t + 512];
    ushort4 o;
    o.x = f2bu(v0.x*scale*w0.x); o.y = f2bu(v0.y*scale*w0.y);
    o.z = f2bu(v0.z*scale*w0.z); o.w = f2bu(v0.w*scale*w0.w);
    hr[t] = o;
    o.x = f2bu(v1.x*scale*w1.x); o.y = f2bu(v1.y*scale*w1.y);
    o.z = f2bu(v1.z*scale*w1.z); o.w = f2bu(v1.w*scale*w1.w);
    hr[t + 256] = o;
    o.x = f2bu(v2.x*scale*w2.x); o.y = f2bu(v2.y*scale*w2.y);
    o.z = f2bu(v2.z*scale*w2.z); o.w = f2bu(v2.w*scale*w2.w);
    hr[t + 512] = o;
    if (t < 128) {
      float4 w3 = wr[t + 768];
      o.x = f2bu(v3.x*scale*w3.x); o.y = f2bu(v3.y*scale*w3.y);
      o.z = f2bu(v3.z*scale*w3.z); o.w = f2bu(v3.w*scale*w3.w);
      hr[t + 768] = o;
    }
    return;
  }

  // ---- rope table ----
  {
    int idx = (blk - NCVT - NTOK) * 256 + t;   // NTOK*64
    int tok = idx >> 6;
    int i = idx & 63;
    float inv = exp2f(-(float)i * (19.931568569324174f / 64.0f));
    float ang = (float)pos[tok] * inv;
    float s, c;
    sincosf(ang, &s, &c);
    tab[idx] = make_float2(c, s);
  }
}

// ================= 256x256 8-phase bf16 GEMM (C = A * B^T) ==================
// R9-verified core (identical to R16). 8 waves (2M x 4N), BK=64, double-
// buffered LDS (128 KiB). Soft barriers; counted VMW() asm orders memory.
// 16x16x32 MFMA. Swizzle slot' = slot ^ (row&7) (conflict-free, R5:
// SQ_LDS_BANK_CONFLICT=0). Stage stagger + vmcnt ledger identical to R9.
// Wave->column remap nmap(j) = (wn>>1)*128 + (wn&1)*32 + (j&1)*16 +
// (j>>1)*64 — each thread holds both halves (j, j+2) of every rope pair.
// MODE 0: rope(acc+bias) fused in fp32; MODE 1: +resid (same nmap bijection).
#define BMT 256
#define BNT 256
#define BKT 64

#define BARRIER() __builtin_amdgcn_s_barrier()
#define VMW(n)    asm volatile("s_waitcnt vmcnt(" #n ")" ::: "memory")

template <int MODE, typename OutT>
__global__ __launch_bounds__(512, 2)
void gemm256(const bf16* __restrict__ A, const bf16* __restrict__ B,
             const float* __restrict__ aux, const float2* __restrict__ tab,
             OutT* __restrict__ C, int M, int N, int K) {
  __shared__ __align__(16) bf16 sA[2][BMT][BKT];   // 64 KiB
  __shared__ __align__(16) bf16 sB[2][BNT][BKT];   // 64 KiB

  const int tid  = threadIdx.x;
  const int wave = tid >> 6;     // 0..7
  const int lane = tid & 63;
  const int wm   = wave >> 2;    // 0..1
  const int wn   = wave & 3;     // 0..3
  const int fr   = lane & 15;
  const int ks   = lane >> 4;
  const int sx   = fr & 7;       // read-side slot XOR = row & 7

  auto nmap = [&](int j) {
    return (wn >> 1) * 128 + (wn & 1) * 32 + ((j & 1) << 4) + ((j >> 1) << 6);
  };

  // bijective XCD swizzle, bn-fast within an XCD (A panel hot in XCD L2)
  const int nwg = gridDim.x;           // 448, % 8 == 0
  const int cpx = nwg >> 3;
  const int swz = (blockIdx.x & 7) * cpx + (blockIdx.x >> 3);
  const int gn  = N / BNT;
  const int bm  = (swz / gn) * BMT;
  const int bn  = (swz % gn) * BNT;

  const bf16* Ab = A + (size_t)bm * K;
  const bf16* Bb = B + (size_t)bn * K;

  const int NT = K / BKT;   // 56 (even)

  const int srw = lane >> 3;    // 0..7  (== row&7)
  const int ssl = lane & 7;

  auto stage64 = [&](const bf16* gpanel, int kt, bf16* ldst, int rbase) {
    const int r  = rbase + wave * 8 + srw;            // tile-local row
    const int sg = ssl ^ srw;                         // pre-swizzled source slot
    const bf16* src = gpanel + (size_t)r * K + (size_t)kt * BKT + sg * 8;
    __builtin_amdgcn_global_load_lds(
        (const __attribute__((address_space(1))) void*)src,
        (__attribute__((address_space(3))) void*)(ldst + (size_t)(wave * 8) * BKT),
        16, 0, 0);
  };
  // kinds: 0=A_H0{0,128}, 1=A_H1{64,192}, 2=B_lo{0,64}, 3=B_hi{128,192}
  auto stage16k = [&](int kind, int buf, int kt) {
    if (kt >= NT) return;
    if (kind == 0)      { stage64(Ab, kt, &sA[buf][0][0],   0);   stage64(Ab, kt, &sA[buf][128][0], 128); }
    else if (kind == 1) { stage64(Ab, kt, &sA[buf][64][0],  64);  stage64(Ab, kt, &sA[buf][192][0], 192); }
    else if (kind == 2) { stage64(Bb, kt, &sB[buf][0][0],   0);   stage64(Bb, kt, &sB[buf][64][0],  64); }
    else                { stage64(Bb, kt, &sB[buf][128][0], 128); stage64(Bb, kt, &sB[buf][192][0], 192); }
  };

  f32x4 acc[8][4];
#pragma unroll
  for (int i = 0; i < 8; ++i)
#pragma unroll
    for (int j = 0; j < 4; ++j)
      acc[i][j] = (f32x4){0.f, 0.f, 0.f, 0.f};

  bf16x8 bfr[4][2];
  bf16x8 afr[2][2];

  auto loadA = [&](int buf, int qq) {
#pragma unroll
    for (int i = 0; i < 2; ++i)
#pragma unroll
      for (int kk = 0; kk < 2; ++kk) {
        const int R  = wm * 128 + qq * 32 + i * 16 + fr;
        const int sp = (kk * 4 + ks) ^ sx;
        afr[i][kk] = *(const bf16x8*)&sA[buf][R][sp * 8];
      }
  };
  auto loadB = [&](int buf) {
#pragma unroll
    for (int j = 0; j < 4; ++j)
#pragma unroll
      for (int kk = 0; kk < 2; ++kk) {
        const int R  = nmap(j) + fr;
        const int sp = (kk * 4 + ks) ^ sx;
        bfr[j][kk] = *(const bf16x8*)&sB[buf][R][sp * 8];
      }
  };
  auto domfma = [&](int q) {
#pragma unroll
    for (int i = 0; i < 2; ++i)
#pragma unroll
      for (int j = 0; j < 4; ++j)
#pragma unroll
        for (int kk = 0; kk < 2; ++kk)
          acc[q * 2 + i][j] = __builtin_amdgcn_mfma_f32_16x16x32_bf16(
              afr[i][kk], bfr[j][kk], acc[q * 2 + i][j], 0, 0, 0);
  };

  // prologue: tile0 complete (8 instr/wave), tile1 B + A_H0 (6 instr/wave)
  stage16k(2, 0, 0); stage16k(3, 0, 0); stage16k(0, 0, 0); stage16k(1, 0, 0);
  stage16k(2, 1, 1); stage16k(3, 1, 1); stage16k(0, 1, 1);
  VMW(6);   // tile0 fully landed
  BARRIER();

  const int nit = NT / 2;   // 28

  for (int it = 0; it < nit; ++it) {
    const bool last = (it == nit - 1);
#pragma unroll
    for (int u = 0; u < 2; ++u) {
#pragma unroll
      for (int q = 0; q < 4; ++q) {
        const int ph = u * 4 + q;
        loadA(u, q);
        if (q == 0) loadB(u);
        if (ph == 0)      stage16k(1, 1, 2 * it + 1);
        else if (ph == 1) stage16k(2, 0, 2 * it + 2);
        else if (ph == 2) stage16k(3, 0, 2 * it + 2);
        else if (ph == 3) stage16k(0, 0, 2 * it + 2);
        else if (ph == 4) stage16k(1, 0, 2 * it + 2);
        else if (ph == 5) stage16k(2, 1, 2 * it + 3);
        else if (ph == 6) stage16k(3, 1, 2 * it + 3);
        else              stage16k(0, 1, 2 * it + 3);
        BARRIER();
        __builtin_amdgcn_s_setprio(1);
        domfma(q);
        __builtin_amdgcn_s_setprio(0);
        if (ph == 3) {
          if (!last) { VMW(6); } else { VMW(2); }
        } else if (ph == 5) {
          if (last)  { VMW(0); }
        } else if (ph == 7) {
          if (!last) { VMW(6); }
        }
        BARRIER();
      }
    }
  }

  // epilogue: C/D layout col-in-frag = lane&15 (fr), row = 4*(lane>>4) + reg
  if (MODE == 0) {
#pragma unroll
    for (int f = 0; f < 8; ++f) {
      const int rb = bm + wm * 128 + f * 16 + ks * 4;
#pragma unroll
      for (int j = 0; j < 2; ++j) {
        const int i_idx = (wn & 1) * 32 + j * 16 + fr;   // pair index in [0,64)
        const int c1 = bn + nmap(j) + fr;
        const int c2 = c1 + 64;
        const float b1 = aux[c1], b2 = aux[c2];
#pragma unroll
        for (int r = 0; r < 4; ++r) {
          const int row = rb + r;
          const float2 cs = tab[(size_t)row * NPAIR + i_idx];
          const float x1 = acc[f][j][r]     + b1;
          const float x2 = acc[f][j + 2][r] + b2;
          stv(&C[(size_t)row * N + c1], x1 * cs.x - x2 * cs.y);
          stv(&C[(size_t)row * N + c2], x2 * cs.x + x1 * cs.y);
        }
      }
    }
  } else {
#pragma unroll
    for (int f = 0; f < 8; ++f) {
      const int rb = bm + wm * 128 + f * 16 + ks * 4;
#pragma unroll
      for (int j = 0; j < 4; ++j) {
        const int col = bn + nmap(j) + fr;
#pragma unroll
        for (int r = 0; r < 4; ++r) {
          const int row = rb + r;
          stv(&C[(size_t)row * N + col],
              acc[f][j][r] + aux[(size_t)row * N + col]);
        }
      }
    }
  }
}

// ---------------- launch ----------------
extern "C" void kernel_launch(void* const* d_in, const int* in_sizes, int n_in,
                              void* d_out, int out_size, void* d_ws, size_t ws_size,
                              hipStream_t stream) {
  (void)in_sizes; (void)n_in; (void)out_size; (void)ws_size;
  const float* x    = (const float*)d_in[0];
  const int*   pos  = (const int*)d_in[1];
  const float* ln_w = (const float*)d_in[2];
  const float* Wq   = (const float*)d_in[3];
  const float* bq   = (const float*)d_in[4];
  const float* Wo   = (const float*)d_in[9];
  float* out = (float*)d_out;

  char* ws = (char*)d_ws;
  size_t off = 0;
  bf16* h    = (bf16*)(ws + off); off += (size_t)NTOK * HIDDEN * sizeof(bf16);
  bf16* q    = (bf16*)(ws + off); off += (size_t)NTOK * NQ * sizeof(bf16);
  bf16* Wqb  = (bf16*)(ws + off); off += (size_t)NQ * HIDDEN * sizeof(bf16);
  bf16* Wob  = (bf16*)(ws + off); off += (size_t)HIDDEN * NQ * sizeof(bf16);
  float2* tab = (float2*)(ws + off); off += (size_t)NTOK * NPAIR * sizeof(float2);

  prep_k<<<NCVT + NTOK + NTAB, 256, 0, stream>>>(Wq, Wqb, Wo, Wob,
                                                 x, ln_w, h, pos, tab);

  const int nblk = (NTOK / BMT) * (NQ / BNT);   // 32 * 14 = 448 (%8 == 0)
  gemm256<0, bf16><<<nblk, 512, 0, stream>>>(h, Wqb, bq, tab, q, NTOK, NQ, HIDDEN);
  gemm256<1, float><<<nblk, 512, 0, stream>>>(q, Wob, x, nullptr, out, NTOK, HIDDEN, NQ);
}

// Round 18
// 480.174 us; speedup vs baseline: 7.2006x; 1.0008x over previous
//
#include <hip/hip_runtime.h>
#include <hip/hip_bf16.h>

// Qwen2 decoder-layer fragment (Q path only — K/V are dead downstream):
//   h = rmsnorm(x, ln_w); q = rope(h@Wq^T + bq); out = q@Wo^T + x
// out fp32 [8192, 3584].
// R18 = R17 (best verified: 480.6 us) + MODE-0 epilogue store reorder:
// stores issued in strict column order (c, c+16, c+64, c+80 per row) so
// adjacent 32B bf16 segments write-combine into 64B lines — R17 counters
// showed GEMM1 WRITE_SIZE = 2x the q size (partial-line writes).
// Everything else byte-identical to R17.

#define HIDDEN   3584
#define NQ       3584
#define NTOK     8192
#define NPAIR    64
#define EPSV     1e-6f

typedef __hip_bfloat16 bf16;
typedef __bf16 bf16x8 __attribute__((ext_vector_type(8)));
typedef float  f32x4  __attribute__((ext_vector_type(4)));

static __device__ __forceinline__ unsigned short f2bu(float f) {
  bf16 h = __float2bfloat16(f);
  return __builtin_bit_cast(unsigned short, h);
}
static __device__ __forceinline__ void stv(float* p, float v) { *p = v; }
static __device__ __forceinline__ void stv(bf16* p, float v) { *p = __float2bfloat16(v); }

// ============ fused prep: weight cvt + rmsnorm + rope table =================
#define N4W   (NQ * HIDDEN / 4)          // 3,211,264 float4s per weight
#define NCVT  (2 * N4W / 256)            // 25088 blocks
#define NTAB  (NTOK * NPAIR / 256)       // 2048 blocks

__global__ __launch_bounds__(256)
void prep_k(const float* __restrict__ Wq, bf16* __restrict__ Wqb,
            const float* __restrict__ Wo, bf16* __restrict__ Wob,
            const float* __restrict__ x, const float* __restrict__ w,
            bf16* __restrict__ h,
            const int* __restrict__ pos, float2* __restrict__ tab) {
  const int blk = blockIdx.x;
  const int t = threadIdx.x;

  if (blk < NCVT) {
    int i = blk * 256 + t;
    const float* s; bf16* d;
    if (i < N4W) { s = Wq; d = Wqb; }
    else         { s = Wo; d = Wob; i -= N4W; }
    float4 f = ((const float4*)s)[i];
    ushort4 o;
    o.x = f2bu(f.x); o.y = f2bu(f.y); o.z = f2bu(f.z); o.w = f2bu(f.w);
    ((ushort4*)d)[i] = o;
    return;
  }

  if (blk < NCVT + NTOK) {
    const int row = blk - NCVT;
    const float4* xr = (const float4*)(x + (size_t)row * HIDDEN);
    const float4* wr = (const float4*)w;

    float4 v0 = xr[t], v1 = xr[t + 256], v2 = xr[t + 512];
    float4 v3 = make_float4(0.f, 0.f, 0.f, 0.f);
    if (t < 128) v3 = xr[t + 768];

    float ss = v0.x*v0.x + v0.y*v0.y + v0.z*v0.z + v0.w*v0.w
             + v1.x*v1.x + v1.y*v1.y + v1.z*v1.z + v1.w*v1.w
             + v2.x*v2.x + v2.y*v2.y + v2.z*v2.z + v2.w*v2.w
             + v3.x*v3.x + v3.y*v3.y + v3.z*v3.z + v3.w*v3.w;

#pragma unroll
    for (int off = 32; off > 0; off >>= 1) ss += __shfl_down(ss, off);
    __shared__ float red[4];
    if ((t & 63) == 0) red[t >> 6] = ss;
    __syncthreads();
    float tot = red[0] + red[1] + red[2] + red[3];
    float scale = rsqrtf(tot * (1.0f / HIDDEN) + EPSV);

    ushort4* hr = (ushort4*)(h + (size_t)row * HIDDEN);
    float4 w0 = wr[t], w1 = wr[t + 256], w2 = wr[t + 512];
    ushort4 o;
    o.x = f2bu(v0.x*scale*w0.x); o.y = f2bu(v0.y*scale*w0.y);
    o.z = f2bu(v0.z*scale*w0.z); o.w = f2bu(v0.w*scale*w0.w);
    hr[t] = o;
    o.x = f2bu(v1.x*scale*w1.x); o.y = f2bu(v1.y*scale*w1.y);
    o.z = f2bu(v1.z*scale*w1.z); o.w = f2bu(v1.w*scale*w1.w);
    hr[t + 256] = o;
    o.x = f2bu(v2.x*scale*w2.x); o.y = f2bu(v2.y*scale*w2.y);
    o.z = f2bu(v2.z*scale*w2.z); o.w = f2bu(v2.w*scale*w2.w);
    hr[t + 512] = o;
    if (t < 128) {
      float4 w3 = wr[t + 768];
      o.x = f2bu(v3.x*scale*w3.x); o.y = f2bu(v3.y*scale*w3.y);
      o.z = f2bu(v3.z*scale*w3.z); o.w = f2bu(v3.w*scale*w3.w);
      hr[t + 768] = o;
    }
    return;
  }

  {
    int idx = (blk - NCVT - NTOK) * 256 + t;   // NTOK*64
    int tok = idx >> 6;
    int i = idx & 63;
    float inv = exp2f(-(float)i * (19.931568569324174f / 64.0f));
    float ang = (float)pos[tok] * inv;
    float s, c;
    sincosf(ang, &s, &c);
    tab[idx] = make_float2(c, s);
  }
}

// ================= 256x256 8-phase bf16 GEMM (C = A * B^T) ==================
// R9-verified core. 8 waves (2M x 4N), BK=64, double-buffered LDS (128 KiB).
// Soft barriers; counted VMW() asm orders memory. 16x16x32 MFMA.
// Swizzle slot' = slot ^ (row&7) (conflict-free, R5: SQ_LDS_BANK_CONFLICT=0).
// Stage stagger + vmcnt ledger identical to R9. nmap(j) pairs rope halves
// thread-locally (j, j+2 = cols c, c+64). MODE 0: rope(acc+bias) fused in
// fp32, stores in strict column order for write-combining; MODE 1: +resid.
#define BMT 256
#define BNT 256
#define BKT 64

#define BARRIER() __builtin_amdgcn_s_barrier()
#define VMW(n)    asm volatile("s_waitcnt vmcnt(" #n ")" ::: "memory")

template <int MODE, typename OutT>
__global__ __launch_bounds__(512, 2)
void gemm256(const bf16* __restrict__ A, const bf16* __restrict__ B,
             const float* __restrict__ aux, const float2* __restrict__ tab,
             OutT* __restrict__ C, int M, int N, int K) {
  __shared__ __align__(16) bf16 sA[2][BMT][BKT];   // 64 KiB
  __shared__ __align__(16) bf16 sB[2][BNT][BKT];   // 64 KiB

  const int tid  = threadIdx.x;
  const int wave = tid >> 6;     // 0..7
  const int lane = tid & 63;
  const int wm   = wave >> 2;    // 0..1
  const int wn   = wave & 3;     // 0..3
  const int fr   = lane & 15;
  const int ks   = lane >> 4;
  const int sx   = fr & 7;       // read-side slot XOR = row & 7

  auto nmap = [&](int j) {
    return (wn >> 1) * 128 + (wn & 1) * 32 + ((j & 1) << 4) + ((j >> 1) << 6);
  };

  // bijective XCD swizzle, bn-fast within an XCD (A panel hot in XCD L2)
  const int nwg = gridDim.x;           // 448, % 8 == 0
  const int cpx = nwg >> 3;
  const int swz = (blockIdx.x & 7) * cpx + (blockIdx.x >> 3);
  const int gn  = N / BNT;
  const int bm  = (swz / gn) * BMT;
  const int bn  = (swz % gn) * BNT;

  const bf16* Ab = A + (size_t)bm * K;
  const bf16* Bb = B + (size_t)bn * K;

  const int NT = K / BKT;   // 56 (even)

  const int srw = lane >> 3;    // 0..7  (== row&7)
  const int ssl = lane & 7;

  auto stage64 = [&](const bf16* gpanel, int kt, bf16* ldst, int rbase) {
    const int r  = rbase + wave * 8 + srw;
    const int sg = ssl ^ srw;
    const bf16* src = gpanel + (size_t)r * K + (size_t)kt * BKT + sg * 8;
    __builtin_amdgcn_global_load_lds(
        (const __attribute__((address_space(1))) void*)src,
        (__attribute__((address_space(3))) void*)(ldst + (size_t)(wave * 8) * BKT),
        16, 0, 0);
  };
  // kinds: 0=A_H0{0,128}, 1=A_H1{64,192}, 2=B_lo{0,64}, 3=B_hi{128,192}
  auto stage16k = [&](int kind, int buf, int kt) {
    if (kt >= NT) return;
    if (kind == 0)      { stage64(Ab, kt, &sA[buf][0][0],   0);   stage64(Ab, kt, &sA[buf][128][0], 128); }
    else if (kind == 1) { stage64(Ab, kt, &sA[buf][64][0],  64);  stage64(Ab, kt, &sA[buf][192][0], 192); }
    else if (kind == 2) { stage64(Bb, kt, &sB[buf][0][0],   0);   stage64(Bb, kt, &sB[buf][64][0],  64); }
    else                { stage64(Bb, kt, &sB[buf][128][0], 128); stage64(Bb, kt, &sB[buf][192][0], 192); }
  };

  f32x4 acc[8][4];
#pragma unroll
  for (int i = 0; i < 8; ++i)
#pragma unroll
    for (int j = 0; j < 4; ++j)
      acc[i][j] = (f32x4){0.f, 0.f, 0.f, 0.f};

  bf16x8 bfr[4][2];
  bf16x8 afr[2][2];

  auto loadA = [&](int buf, int qq) {
#pragma unroll
    for (int i = 0; i < 2; ++i)
#pragma unroll
      for (int kk = 0; kk < 2; ++kk) {
        const int R  = wm * 128 + qq * 32 + i * 16 + fr;
        const int sp = (kk * 4 + ks) ^ sx;
        afr[i][kk] = *(const bf16x8*)&sA[buf][R][sp * 8];
      }
  };
  auto loadB = [&](int buf) {
#pragma unroll
    for (int j = 0; j < 4; ++j)
#pragma unroll
      for (int kk = 0; kk < 2; ++kk) {
        const int R  = nmap(j) + fr;
        const int sp = (kk * 4 + ks) ^ sx;
        bfr[j][kk] = *(const bf16x8*)&sB[buf][R][sp * 8];
      }
  };
  auto domfma = [&](int q) {
#pragma unroll
    for (int i = 0; i < 2; ++i)
#pragma unroll
      for (int j = 0; j < 4; ++j)
#pragma unroll
        for (int kk = 0; kk < 2; ++kk)
          acc[q * 2 + i][j] = __builtin_amdgcn_mfma_f32_16x16x32_bf16(
              afr[i][kk], bfr[j][kk], acc[q * 2 + i][j], 0, 0, 0);
  };

  // prologue: tile0 complete (8 instr/wave), tile1 B + A_H0 (6 instr/wave)
  stage16k(2, 0, 0); stage16k(3, 0, 0); stage16k(0, 0, 0); stage16k(1, 0, 0);
  stage16k(2, 1, 1); stage16k(3, 1, 1); stage16k(0, 1, 1);
  VMW(6);   // tile0 fully landed
  BARRIER();

  const int nit = NT / 2;   // 28

  for (int it = 0; it < nit; ++it) {
    const bool last = (it == nit - 1);
#pragma unroll
    for (int u = 0; u < 2; ++u) {
#pragma unroll
      for (int q = 0; q < 4; ++q) {
        const int ph = u * 4 + q;
        loadA(u, q);
        if (q == 0) loadB(u);
        if (ph == 0)      stage16k(1, 1, 2 * it + 1);
        else if (ph == 1) stage16k(2, 0, 2 * it + 2);
        else if (ph == 2) stage16k(3, 0, 2 * it + 2);
        else if (ph == 3) stage16k(0, 0, 2 * it + 2);
        else if (ph == 4) stage16k(1, 0, 2 * it + 2);
        else if (ph == 5) stage16k(2, 1, 2 * it + 3);
        else if (ph == 6) stage16k(3, 1, 2 * it + 3);
        else              stage16k(0, 1, 2 * it + 3);
        BARRIER();
        __builtin_amdgcn_s_setprio(1);
        domfma(q);
        __builtin_amdgcn_s_setprio(0);
        if (ph == 3) {
          if (!last) { VMW(6); } else { VMW(2); }
        } else if (ph == 5) {
          if (last)  { VMW(0); }
        } else if (ph == 7) {
          if (!last) { VMW(6); }
        }
        BARRIER();
      }
    }
  }

  // epilogue: C/D layout col-in-frag = lane&15 (fr), row = 4*(lane>>4) + reg
  if (MODE == 0) {
    // fused rope; stores in strict column order (c, c+16, c+64, c+80) per
    // row so adjacent 32B bf16 segments write-combine into 64B lines.
    const int cb = bn + (wn >> 1) * 128 + (wn & 1) * 32 + fr;  // = nmap(0)+fr
#pragma unroll
    for (int f = 0; f < 8; ++f) {
      const int rb = bm + wm * 128 + f * 16 + ks * 4;
      const float b0a = aux[cb];        // j=0, c1
      const float b1a = aux[cb + 16];   // j=1, c1
      const float b0b = aux[cb + 64];   // j=0, c2
      const float b1b = aux[cb + 80];   // j=1, c2
      const int i0 = (wn & 1) * 32 + fr;        // pair index, j=0
      const int i1 = i0 + 16;                   // pair index, j=1
#pragma unroll
      for (int r = 0; r < 4; ++r) {
        const int row = rb + r;
        const float2 cs0 = tab[(size_t)row * NPAIR + i0];
        const float2 cs1 = tab[(size_t)row * NPAIR + i1];
        const float x10 = acc[f][0][r] + b0a, x20 = acc[f][2][r] + b0b;
        const float x11 = acc[f][1][r] + b1a, x21 = acc[f][3][r] + b1b;
        OutT* cr = &C[(size_t)row * N + cb];
        stv(&cr[0],  x10 * cs0.x - x20 * cs0.y);
        stv(&cr[16], x11 * cs1.x - x21 * cs1.y);
        stv(&cr[64], x20 * cs0.x + x10 * cs0.y);
        stv(&cr[80], x21 * cs1.x + x11 * cs1.y);
      }
    }
  } else {
#pragma unroll
    for (int f = 0; f < 8; ++f) {
      const int rb = bm + wm * 128 + f * 16 + ks * 4;
#pragma unroll
      for (int j = 0; j < 4; ++j) {
        const int col = bn + nmap(j) + fr;
#pragma unroll
        for (int r = 0; r < 4; ++r) {
          const int row = rb + r;
          stv(&C[(size_t)row * N + col],
              acc[f][j][r] + aux[(size_t)row * N + col]);
        }
      }
    }
  }
}

// ---------------- launch ----------------
extern "C" void kernel_launch(void* const* d_in, const int* in_sizes, int n_in,
                              void* d_out, int out_size, void* d_ws, size_t ws_size,
                              hipStream_t stream) {
  (void)in_sizes; (void)n_in; (void)out_size; (void)ws_size;
  const float* x    = (const float*)d_in[0];
  const int*   pos  = (const int*)d_in[1];
  const float* ln_w = (const float*)d_in[2];
  const float* Wq   = (const float*)d_in[3];
  const float* bq   = (const float*)d_in[4];
  const float* Wo   = (const float*)d_in[9];
  float* out = (float*)d_out;

  char* ws = (char*)d_ws;
  size_t off = 0;
  bf16* h    = (bf16*)(ws + off); off += (size_t)NTOK * HIDDEN * sizeof(bf16);
  bf16* q    = (bf16*)(ws + off); off += (size_t)NTOK * NQ * sizeof(bf16);
  bf16* Wqb  = (bf16*)(ws + off); off += (size_t)NQ * HIDDEN * sizeof(bf16);
  bf16* Wob  = (bf16*)(ws + off); off += (size_t)HIDDEN * NQ * sizeof(bf16);
  float2* tab = (float2*)(ws + off); off += (size_t)NTOK * NPAIR * sizeof(float2);

  prep_k<<<NCVT + NTOK + NTAB, 256, 0, stream>>>(Wq, Wqb, Wo, Wob,
                                                 x, ln_w, h, pos, tab);

  const int nblk = (NTOK / BMT) * (NQ / BNT);   // 32 * 14 = 448 (%8 == 0)
  gemm256<0, bf16><<<nblk, 512, 0, stream>>>(h, Wqb, bq, tab, q, NTOK, NQ, HIDDEN);
  gemm256<1, float><<<nblk, 512, 0, stream>>>(q, Wob, x, nullptr, out, NTOK, HIDDEN, NQ);
}